// Round 3
// baseline (248.622 us; speedup 1.0000x reference)
//
#include <hip/hip_runtime.h>
#include <float.h>
#include <math.h>

#define Bc 512
#define Sc 100
#define Hc 1024
#define Ac 128
#define Nc 8

// ---------------- K0a: positional-encoding table pe[S][H] ----------------
__global__ __launch_bounds__(256) void pe_kernel(float* __restrict__ pe){
  int s = blockIdx.x;
  int t = threadIdx.x;
  const float fac = (float)(-9.210340371976184 / 1024.0);  // -ln(10000)/H
  for(int i = t; i < Hc/2; i += 256){
    float div = expf((float)(2*i) * fac);
    float a = (float)s * div;
    pe[s*Hc + 2*i]     = sinf(a);
    pe[s*Hc + 2*i + 1] = cosf(a);
  }
}

// ---------------- K0b: pesum[h] = sum_s pe[s][h] ----------------
__global__ __launch_bounds__(256) void pesum_kernel(const float* __restrict__ pe, float* __restrict__ pesum){
  int h = blockIdx.x*256 + threadIdx.x;
  float acc = 0.f;
  for(int s = 0; s < Sc; ++s) acc += pe[s*Hc + h];
  pesum[h] = acc;
}

// ---------------- K1: xsp[b][q][h] = sum_{s in quarter q} x[b,s,h]  (+pesum at q==0) ----------------
__global__ __launch_bounds__(256) void xsum_kernel(const float* __restrict__ x, const float* __restrict__ pesum,
                                                   float* __restrict__ xsp){
  int b = blockIdx.x;
  int q = blockIdx.y;
  int t = threadIdx.x;
  const float4* xr = (const float4*)(x + (size_t)b*Sc*Hc);
  float4 acc;
  if(q == 0) acc = ((const float4*)pesum)[t];
  else       acc = make_float4(0.f,0.f,0.f,0.f);
  int s0 = q*25;
  #pragma unroll 5
  for(int s = s0; s < s0+25; ++s){
    float4 v = xr[s*(Hc/4) + t];
    acc.x += v.x; acc.y += v.y; acc.z += v.z; acc.w += v.w;
  }
  ((float4*)(xsp + ((size_t)b*4 + q)*Hc))[t] = acc;
}

// ---------------- K2: Ksum[b][j] = sum_h (sum_q xsp[b][q][h]) * Wk[j][h] ----------------
__global__ __launch_bounds__(256) void ksum_gemm(const float* __restrict__ xs, const float* __restrict__ Wk,
                                                 float* __restrict__ Ksum){
  __shared__ float As[32][33];
  __shared__ float Bs[32][68];
  int t = threadIdx.x;
  int j0 = blockIdx.x*64, b0 = blockIdx.y*32;
  int bi = (t>>4)*2;
  int j4 = (t&15)*4;
  float acc[2][4] = {{0,0,0,0},{0,0,0,0}};
  int ra = t>>3, ca = t&7;
  for(int k0 = 0; k0 < Hc; k0 += 32){
    const float* xa = xs + (size_t)(b0+ra)*(4*Hc) + k0 + ca*4;
    float4 a4 = *(const float4*)(xa);
    float4 p1 = *(const float4*)(xa + Hc);
    float4 p2 = *(const float4*)(xa + 2*Hc);
    float4 p3 = *(const float4*)(xa + 3*Hc);
    a4.x += p1.x + p2.x + p3.x;
    a4.y += p1.y + p2.y + p3.y;
    a4.z += p1.z + p2.z + p3.z;
    a4.w += p1.w + p2.w + p3.w;
    As[ca*4+0][ra]=a4.x; As[ca*4+1][ra]=a4.y; As[ca*4+2][ra]=a4.z; As[ca*4+3][ra]=a4.w;
    #pragma unroll
    for(int ph = 0; ph < 2; ++ph){
      int q = t + ph*256;
      int r = q>>3, c = q&7;
      float4 b4 = *(const float4*)(Wk + (size_t)(j0+r)*Hc + k0 + c*4);
      Bs[c*4+0][r]=b4.x; Bs[c*4+1][r]=b4.y; Bs[c*4+2][r]=b4.z; Bs[c*4+3][r]=b4.w;
    }
    __syncthreads();
    #pragma unroll
    for(int kk = 0; kk < 32; ++kk){
      float a0 = As[kk][bi], a1 = As[kk][bi+1];
      float4 bq = *(const float4*)&Bs[kk][j4];
      acc[0][0]=fmaf(a0,bq.x,acc[0][0]); acc[0][1]=fmaf(a0,bq.y,acc[0][1]);
      acc[0][2]=fmaf(a0,bq.z,acc[0][2]); acc[0][3]=fmaf(a0,bq.w,acc[0][3]);
      acc[1][0]=fmaf(a1,bq.x,acc[1][0]); acc[1][1]=fmaf(a1,bq.y,acc[1][1]);
      acc[1][2]=fmaf(a1,bq.z,acc[1][2]); acc[1][3]=fmaf(a1,bq.w,acc[1][3]);
    }
    __syncthreads();
  }
  #pragma unroll
  for(int ii = 0; ii < 2; ++ii){
    float4 o = make_float4(acc[ii][0],acc[ii][1],acc[ii][2],acc[ii][3]);
    *(float4*)(Ksum + (size_t)(b0+bi+ii)*Hc + j0 + j4) = o;
  }
}

// ---------------- K3: v[b][n][h] = sum_a Ksum[b][n*A+a] * Wq[n*A+a][h] ----------------
__global__ __launch_bounds__(256) void v_gemm(const float* __restrict__ Ksum, const float* __restrict__ Wq,
                                              float* __restrict__ v){
  __shared__ float As[32][33];
  __shared__ float Bs[32][68];
  int t = threadIdx.x;
  int h0 = blockIdx.x*64, b0 = blockIdx.y*32, n = blockIdx.z;
  int bi = (t>>4)*2;
  int j4 = (t&15)*4;
  float acc[2][4] = {{0,0,0,0},{0,0,0,0}};
  int ra = t>>3, ca = t&7;
  for(int k0 = 0; k0 < Ac; k0 += 32){
    float4 a4 = *(const float4*)(Ksum + (size_t)(b0+ra)*Hc + n*Ac + k0 + ca*4);
    As[ca*4+0][ra]=a4.x; As[ca*4+1][ra]=a4.y; As[ca*4+2][ra]=a4.z; As[ca*4+3][ra]=a4.w;
    #pragma unroll
    for(int ph = 0; ph < 2; ++ph){
      int q = t + ph*256;
      int r = q>>4, c = q&15;
      float4 b4 = *(const float4*)(Wq + (size_t)(n*Ac + k0 + r)*Hc + h0 + c*4);
      *(float4*)&Bs[r][c*4] = b4;
    }
    __syncthreads();
    #pragma unroll
    for(int kk = 0; kk < 32; ++kk){
      float a0 = As[kk][bi], a1 = As[kk][bi+1];
      float4 bq = *(const float4*)&Bs[kk][j4];
      acc[0][0]=fmaf(a0,bq.x,acc[0][0]); acc[0][1]=fmaf(a0,bq.y,acc[0][1]);
      acc[0][2]=fmaf(a0,bq.z,acc[0][2]); acc[0][3]=fmaf(a0,bq.w,acc[0][3]);
      acc[1][0]=fmaf(a1,bq.x,acc[1][0]); acc[1][1]=fmaf(a1,bq.y,acc[1][1]);
      acc[1][2]=fmaf(a1,bq.z,acc[1][2]); acc[1][3]=fmaf(a1,bq.w,acc[1][3]);
    }
    __syncthreads();
  }
  #pragma unroll
  for(int ii = 0; ii < 2; ++ii){
    float4 o = make_float4(acc[ii][0],acc[ii][1],acc[ii][2],acc[ii][3]);
    *(float4*)(v + ((size_t)(b0+bi+ii)*Nc + n)*Hc + h0 + j4) = o;
  }
}

// ---------------- K4: logits -> +gumbel -> argmax_s -> gather rows of x ----------------
// One block (512 thr = 8 waves) per b. NO LDS staging of v: v[b,n,kc] is wave-uniform,
// read straight from global (compiler scalarizes to s_load; worst case L1-resident 32KB).
// Wave w owns k-eighth; lane owns 2 s-rows (lane, lane+64). part[] combine; fused gather.
__global__ __launch_bounds__(512) void attn_kernel(const float* __restrict__ x, const float* __restrict__ pe,
                                                   const float* __restrict__ v, const float* __restrict__ g,
                                                   float* __restrict__ out){
  __shared__ float part[8][Nc][128];  // 32 KB  [k-eighth][head][s]
  __shared__ int sidx[Nc];
  int b = blockIdx.x;
  int t = threadIdx.x;
  int w = t >> 6, lane = t & 63;       // w = k-eighth index 0..7
  int r0 = lane;                        // s rows 0..63 (always valid, S=100)
  int r1 = lane + 64;                   // 64..127; >=100 are dummies
  int r1c = (r1 < Sc) ? r1 : (Sc-1);

  const float4* x0 = (const float4*)(x  + ((size_t)b*Sc + r0)*Hc);
  const float4* x1 = (const float4*)(x  + ((size_t)b*Sc + r1c)*Hc);
  const float4* p0 = (const float4*)(pe + (size_t)r0*Hc);
  const float4* p1 = (const float4*)(pe + (size_t)r1c*Hc);
  const float4* vb = (const float4*)(v  + (size_t)b*Nc*Hc);   // wave-uniform reads

  float a0[Nc], a1[Nc];
  #pragma unroll
  for(int n = 0; n < Nc; ++n){ a0[n] = 0.f; a1[n] = 0.f; }

  int kc0 = w*32;                       // float4 index; each wave owns 32 of 256
  #pragma unroll 4
  for(int kc = kc0; kc < kc0 + 32; ++kc){
    float4 xv0 = x0[kc], pv0 = p0[kc];
    float4 xv1 = x1[kc], pv1 = p1[kc];
    float4 e0 = make_float4(xv0.x+pv0.x, xv0.y+pv0.y, xv0.z+pv0.z, xv0.w+pv0.w);
    float4 e1 = make_float4(xv1.x+pv1.x, xv1.y+pv1.y, xv1.z+pv1.z, xv1.w+pv1.w);
    #pragma unroll
    for(int n = 0; n < Nc; ++n){
      float4 vv = vb[n*(Hc/4) + kc];    // uniform -> scalar path
      a0[n] = fmaf(e0.x, vv.x, a0[n]);
      a0[n] = fmaf(e0.y, vv.y, a0[n]);
      a0[n] = fmaf(e0.z, vv.z, a0[n]);
      a0[n] = fmaf(e0.w, vv.w, a0[n]);
      a1[n] = fmaf(e1.x, vv.x, a1[n]);
      a1[n] = fmaf(e1.y, vv.y, a1[n]);
      a1[n] = fmaf(e1.z, vv.z, a1[n]);
      a1[n] = fmaf(e1.w, vv.w, a1[n]);
    }
  }
  #pragma unroll
  for(int n = 0; n < Nc; ++n){
    part[w][n][r0] = a0[n];             // stride-1 across lanes, conflict-free
    part[w][n][r1] = a1[n];
  }
  __syncthreads();

  // phase 2: y = dot/3200 + gumbel; argmax over s. One wave per head n=w.
  int n = w, j = lane;
  float best = -FLT_MAX; int bidx = 0;
  #pragma unroll
  for(int i = 0; i < 2; ++i){
    int s2 = j + 64*i;
    if(s2 < Sc){
      float dot = 0.f;
      #pragma unroll
      for(int q = 0; q < 8; ++q) dot += part[q][n][s2];
      float y = dot/3200.0f + g[(size_t)(b*Nc + n)*Sc + s2];
      if(y > best){ best = y; bidx = s2; }   // strict > keeps first index (jnp tie rule)
    }
  }
  #pragma unroll
  for(int m = 32; m >= 1; m >>= 1){
    float ob = __shfl_xor(best, m, 64);
    int   oi = __shfl_xor(bidx, m, 64);
    if(ob > best || (ob == best && oi < bidx)){ best = ob; bidx = oi; }
  }
  if(j == 0) sidx[n] = bidx;
  __syncthreads();

  // phase 3: out[b,n,:] = x[b, s*, :]  (2048 float4 over 512 threads)
  const float4* xb = (const float4*)(x + (size_t)b*Sc*Hc);
  float4* ob4 = (float4*)(out + (size_t)b*Nc*Hc);
  #pragma unroll
  for(int i = 0; i < 4; ++i){
    int idx = i*512 + t;
    int nn = idx >> 8, c = idx & 255;
    ob4[idx] = xb[sidx[nn]*256 + c];
  }
}

extern "C" void kernel_launch(void* const* d_in, const int* in_sizes, int n_in,
                              void* d_out, int out_size, void* d_ws, size_t ws_size,
                              hipStream_t stream) {
  const float* x  = (const float*)d_in[0];   // [512,100,1024]
  const float* Wq = (const float*)d_in[1];   // [1024,1024]
  const float* Wk = (const float*)d_in[2];   // [1024,1024]
  const float* g  = (const float*)d_in[3];   // [4096,100]
  float* out = (float*)d_out;                // [512,8,1024]

  char* ws = (char*)d_ws;
  float* pe    = (float*)(ws);                //    409,600 B
  float* pesum = (float*)(ws +    409600);    //      4,096 B
  float* xsp   = (float*)(ws +    413696);    //  8,388,608 B  [512][4][1024]
  float* Ksum  = (float*)(ws +   8802304);    //  2,097,152 B
  float* v     = (float*)(ws +  10899456);    // 16,777,216 B  (total ~27.7 MB)

  pe_kernel   <<<100, 256, 0, stream>>>(pe);
  pesum_kernel<<<4,   256, 0, stream>>>(pe, pesum);
  xsum_kernel <<<dim3(512,4),   256, 0, stream>>>(x, pesum, xsp);
  ksum_gemm   <<<dim3(16,16),   256, 0, stream>>>(xsp, Wk, Ksum);
  v_gemm      <<<dim3(16,16,8), 256, 0, stream>>>(Ksum, Wq, v);
  attn_kernel <<<512, 512, 0, stream>>>(x, pe, v, g, out);
}

// Round 4
// 154.550 us; speedup vs baseline: 1.6087x; 1.6087x over previous
//
#include <hip/hip_runtime.h>
#include <float.h>
#include <math.h>

#define Bc 512
#define Sc 100
#define Hc 1024
#define Ac 128
#define Nc 8

// ---------------- K0a: positional-encoding table pe[S][H] ----------------
__global__ __launch_bounds__(256) void pe_kernel(float* __restrict__ pe){
  int s = blockIdx.x;
  int t = threadIdx.x;
  const float fac = (float)(-9.210340371976184 / 1024.0);  // -ln(10000)/H
  for(int i = t; i < Hc/2; i += 256){
    float div = expf((float)(2*i) * fac);
    float a = (float)s * div;
    pe[s*Hc + 2*i]     = sinf(a);
    pe[s*Hc + 2*i + 1] = cosf(a);
  }
}

// ---------------- K0b: pesum[h] = sum_s pe[s][h] ----------------
__global__ __launch_bounds__(256) void pesum_kernel(const float* __restrict__ pe, float* __restrict__ pesum){
  int h = blockIdx.x*256 + threadIdx.x;
  float acc = 0.f;
  for(int s = 0; s < Sc; ++s) acc += pe[s*Hc + h];
  pesum[h] = acc;
}

// ---------------- K1: xsp[b][q][h] = sum_{s in quarter q} x[b,s,h]  (+pesum at q==0) ----------------
__global__ __launch_bounds__(256) void xsum_kernel(const float* __restrict__ x, const float* __restrict__ pesum,
                                                   float* __restrict__ xsp){
  int b = blockIdx.x;
  int q = blockIdx.y;
  int t = threadIdx.x;
  const float4* xr = (const float4*)(x + (size_t)b*Sc*Hc);
  float4 acc;
  if(q == 0) acc = ((const float4*)pesum)[t];
  else       acc = make_float4(0.f,0.f,0.f,0.f);
  int s0 = q*25;
  #pragma unroll 5
  for(int s = s0; s < s0+25; ++s){
    float4 v = xr[s*(Hc/4) + t];
    acc.x += v.x; acc.y += v.y; acc.z += v.z; acc.w += v.w;
  }
  ((float4*)(xsp + ((size_t)b*4 + q)*Hc))[t] = acc;
}

// ---------------- K2: Ksum[b][j] = sum_h (sum_q xsp[b][q][h]) * Wk[j][h] ----------------
__global__ __launch_bounds__(256) void ksum_gemm(const float* __restrict__ xs, const float* __restrict__ Wk,
                                                 float* __restrict__ Ksum){
  __shared__ float As[32][33];
  __shared__ float Bs[32][68];
  int t = threadIdx.x;
  int j0 = blockIdx.x*64, b0 = blockIdx.y*32;
  int bi = (t>>4)*2;
  int j4 = (t&15)*4;
  float acc[2][4] = {{0,0,0,0},{0,0,0,0}};
  int ra = t>>3, ca = t&7;
  for(int k0 = 0; k0 < Hc; k0 += 32){
    const float* xa = xs + (size_t)(b0+ra)*(4*Hc) + k0 + ca*4;
    float4 a4 = *(const float4*)(xa);
    float4 p1 = *(const float4*)(xa + Hc);
    float4 p2 = *(const float4*)(xa + 2*Hc);
    float4 p3 = *(const float4*)(xa + 3*Hc);
    a4.x += p1.x + p2.x + p3.x;
    a4.y += p1.y + p2.y + p3.y;
    a4.z += p1.z + p2.z + p3.z;
    a4.w += p1.w + p2.w + p3.w;
    As[ca*4+0][ra]=a4.x; As[ca*4+1][ra]=a4.y; As[ca*4+2][ra]=a4.z; As[ca*4+3][ra]=a4.w;
    #pragma unroll
    for(int ph = 0; ph < 2; ++ph){
      int q = t + ph*256;
      int r = q>>3, c = q&7;
      float4 b4 = *(const float4*)(Wk + (size_t)(j0+r)*Hc + k0 + c*4);
      Bs[c*4+0][r]=b4.x; Bs[c*4+1][r]=b4.y; Bs[c*4+2][r]=b4.z; Bs[c*4+3][r]=b4.w;
    }
    __syncthreads();
    #pragma unroll
    for(int kk = 0; kk < 32; ++kk){
      float a0 = As[kk][bi], a1 = As[kk][bi+1];
      float4 bq = *(const float4*)&Bs[kk][j4];
      acc[0][0]=fmaf(a0,bq.x,acc[0][0]); acc[0][1]=fmaf(a0,bq.y,acc[0][1]);
      acc[0][2]=fmaf(a0,bq.z,acc[0][2]); acc[0][3]=fmaf(a0,bq.w,acc[0][3]);
      acc[1][0]=fmaf(a1,bq.x,acc[1][0]); acc[1][1]=fmaf(a1,bq.y,acc[1][1]);
      acc[1][2]=fmaf(a1,bq.z,acc[1][2]); acc[1][3]=fmaf(a1,bq.w,acc[1][3]);
    }
    __syncthreads();
  }
  #pragma unroll
  for(int ii = 0; ii < 2; ++ii){
    float4 o = make_float4(acc[ii][0],acc[ii][1],acc[ii][2],acc[ii][3]);
    *(float4*)(Ksum + (size_t)(b0+bi+ii)*Hc + j0 + j4) = o;
  }
}

// ---------------- K3: v[b][n][h] = sum_a Ksum[b][n*A+a] * Wq[n*A+a][h] ----------------
__global__ __launch_bounds__(256) void v_gemm(const float* __restrict__ Ksum, const float* __restrict__ Wq,
                                              float* __restrict__ v){
  __shared__ float As[32][33];
  __shared__ float Bs[32][68];
  int t = threadIdx.x;
  int h0 = blockIdx.x*64, b0 = blockIdx.y*32, n = blockIdx.z;
  int bi = (t>>4)*2;
  int j4 = (t&15)*4;
  float acc[2][4] = {{0,0,0,0},{0,0,0,0}};
  int ra = t>>3, ca = t&7;
  for(int k0 = 0; k0 < Ac; k0 += 32){
    float4 a4 = *(const float4*)(Ksum + (size_t)(b0+ra)*Hc + n*Ac + k0 + ca*4);
    As[ca*4+0][ra]=a4.x; As[ca*4+1][ra]=a4.y; As[ca*4+2][ra]=a4.z; As[ca*4+3][ra]=a4.w;
    #pragma unroll
    for(int ph = 0; ph < 2; ++ph){
      int q = t + ph*256;
      int r = q>>4, c = q&15;
      float4 b4 = *(const float4*)(Wq + (size_t)(n*Ac + k0 + r)*Hc + h0 + c*4);
      *(float4*)&Bs[r][c*4] = b4;
    }
    __syncthreads();
    #pragma unroll
    for(int kk = 0; kk < 32; ++kk){
      float a0 = As[kk][bi], a1 = As[kk][bi+1];
      float4 bq = *(const float4*)&Bs[kk][j4];
      acc[0][0]=fmaf(a0,bq.x,acc[0][0]); acc[0][1]=fmaf(a0,bq.y,acc[0][1]);
      acc[0][2]=fmaf(a0,bq.z,acc[0][2]); acc[0][3]=fmaf(a0,bq.w,acc[0][3]);
      acc[1][0]=fmaf(a1,bq.x,acc[1][0]); acc[1][1]=fmaf(a1,bq.y,acc[1][1]);
      acc[1][2]=fmaf(a1,bq.z,acc[1][2]); acc[1][3]=fmaf(a1,bq.w,acc[1][3]);
    }
    __syncthreads();
  }
  #pragma unroll
  for(int ii = 0; ii < 2; ++ii){
    float4 o = make_float4(acc[ii][0],acc[ii][1],acc[ii][2],acc[ii][3]);
    *(float4*)(v + ((size_t)(b0+bi+ii)*Nc + n)*Hc + h0 + j4) = o;
  }
}

// ---------------- K4: x.v logits -> +gumbel -> argmax_s -> gather rows of x ----------------
// One block (1024 thr = 16 waves) per b. Per k-tile (64 floats): stage (x+pe) tile
// [100 s][64 k] into LDS via XOR-swizzled 16B slots (coalesced global, conflict-free
// column reads). Wave = (sh, kq): lanes->s (row per lane), k wave-UNIFORM ->
// v[b,n,k] read via the SCALAR pipe (readfirstlane'd wave id + __restrict__ const).
__global__ __launch_bounds__(1024) void attn_kernel(const float* __restrict__ x, const float* __restrict__ pe,
                                                    const float* __restrict__ v, const float* __restrict__ g,
                                                    float* __restrict__ out){
  __shared__ float4 tile[1600];        // [r<100][16 slots], 16B-slot XOR swizzle, 25.6 KB
  __shared__ float part[8][Nc][104];   // [kq][n][s] 26.6 KB
  __shared__ int sidx[Nc];
  const int b = blockIdx.x;
  const int t = threadIdx.x;
  const int lane = t & 63;
  const int w  = __builtin_amdgcn_readfirstlane(t >> 6);  // wave id 0..15, SGPR
  const int kq = w & 7, sh = w >> 3;

  // staging indices (flat over 1600 float4s)
  const int r1 = t >> 4, c1 = t & 15;
  const bool has2 = (t < 576);
  const int e2 = t + 1024;
  const int r2 = e2 >> 4, c2 = e2 & 15;

  const float* xb = x + (size_t)b*Sc*Hc;
  const float* vb = v + (size_t)b*Nc*Hc;

  // compute-side row (lanes->s)
  int rw = sh*64 + lane;               // 0..127
  int r  = (rw < Sc) ? rw : (Sc-1);
  const bool valid = (rw < Sc);

  float acc[Nc];
  #pragma unroll
  for(int n = 0; n < Nc; ++n) acc[n] = 0.f;

  // prologue: loads for tile 0
  float4 xv1 = *(const float4*)(xb + r1*Hc + c1*4);
  float4 pv1 = *(const float4*)(pe + r1*Hc + c1*4);
  float4 xv2 = make_float4(0,0,0,0), pv2 = make_float4(0,0,0,0);
  if(has2){ xv2 = *(const float4*)(xb + r2*Hc + c2*4);
            pv2 = *(const float4*)(pe + r2*Hc + c2*4); }

  for(int kt = 0; kt < 16; ++kt){
    __syncthreads();                    // previous tile's reads complete
    tile[r1*16 + (c1 ^ (r1&7))] = make_float4(xv1.x+pv1.x, xv1.y+pv1.y, xv1.z+pv1.z, xv1.w+pv1.w);
    if(has2)
      tile[r2*16 + (c2 ^ (r2&7))] = make_float4(xv2.x+pv2.x, xv2.y+pv2.y, xv2.z+pv2.z, xv2.w+pv2.w);
    // issue next tile's loads (in flight during compute)
    if(kt < 15){
      int ko = (kt+1)*64;
      xv1 = *(const float4*)(xb + r1*Hc + ko + c1*4);
      pv1 = *(const float4*)(pe + r1*Hc + ko + c1*4);
      if(has2){ xv2 = *(const float4*)(xb + r2*Hc + ko + c2*4);
                pv2 = *(const float4*)(pe + r2*Hc + ko + c2*4); }
    }
    __syncthreads();                    // tile staged
    #pragma unroll
    for(int j = 0; j < 2; ++j){
      float4 xe = tile[r*16 + ((kq*2 + j) ^ (r&7))];
      const float* vk = vb + kt*64 + kq*8 + j*4;   // wave-uniform -> scalar loads
      #pragma unroll
      for(int n = 0; n < Nc; ++n){
        const float* vn = vk + n*Hc;
        acc[n] = fmaf(xe.x, vn[0], acc[n]);
        acc[n] = fmaf(xe.y, vn[1], acc[n]);
        acc[n] = fmaf(xe.z, vn[2], acc[n]);
        acc[n] = fmaf(xe.w, vn[3], acc[n]);
      }
    }
  }
  if(valid){
    #pragma unroll
    for(int n = 0; n < Nc; ++n) part[kq][n][rw] = acc[n];
  }
  __syncthreads();

  // phase 2: y = dot/3200 + gumbel; argmax over s. Waves 0..7, one head each.
  if(w < Nc){
    int n = w, j = lane;
    float best = -FLT_MAX; int bidx = 0;
    #pragma unroll
    for(int i = 0; i < 2; ++i){
      int s2 = j + 64*i;
      if(s2 < Sc){
        float dot = 0.f;
        #pragma unroll
        for(int q = 0; q < 8; ++q) dot += part[q][n][s2];
        float y = dot/3200.0f + g[(size_t)(b*Nc + n)*Sc + s2];
        if(y > best){ best = y; bidx = s2; }   // strict > keeps first index (jnp tie rule)
      }
    }
    #pragma unroll
    for(int m = 32; m >= 1; m >>= 1){
      float ob = __shfl_xor(best, m, 64);
      int   oi = __shfl_xor(bidx, m, 64);
      if(ob > best || (ob == best && oi < bidx)){ best = ob; bidx = oi; }
    }
    if(j == 0) sidx[n] = bidx;
  }
  __syncthreads();

  // phase 3: out[b,n,:] = x[b, s*, :]  (2048 float4 over 1024 threads)
  const float4* xb4 = (const float4*)xb;
  float4* ob4 = (float4*)(out + (size_t)b*Nc*Hc);
  #pragma unroll
  for(int i = 0; i < 2; ++i){
    int idx = i*1024 + t;
    int nn = idx >> 8, c = idx & 255;
    ob4[idx] = xb4[sidx[nn]*256 + c];
  }
}

extern "C" void kernel_launch(void* const* d_in, const int* in_sizes, int n_in,
                              void* d_out, int out_size, void* d_ws, size_t ws_size,
                              hipStream_t stream) {
  const float* x  = (const float*)d_in[0];   // [512,100,1024]
  const float* Wq = (const float*)d_in[1];   // [1024,1024]
  const float* Wk = (const float*)d_in[2];   // [1024,1024]
  const float* g  = (const float*)d_in[3];   // [4096,100]
  float* out = (float*)d_out;                // [512,8,1024]

  char* ws = (char*)d_ws;
  float* pe    = (float*)(ws);                //    409,600 B
  float* pesum = (float*)(ws +    409600);    //      4,096 B
  float* xsp   = (float*)(ws +    413696);    //  8,388,608 B  [512][4][1024]
  float* Ksum  = (float*)(ws +   8802304);    //  2,097,152 B
  float* v     = (float*)(ws +  10899456);    // 16,777,216 B  (total ~27.7 MB)

  pe_kernel   <<<100, 256, 0, stream>>>(pe);
  pesum_kernel<<<4,   256, 0, stream>>>(pe, pesum);
  xsum_kernel <<<dim3(512,4),   256, 0, stream>>>(x, pesum, xsp);
  ksum_gemm   <<<dim3(16,16),   256, 0, stream>>>(xsp, Wk, Ksum);
  v_gemm      <<<dim3(16,16,8), 256, 0, stream>>>(Ksum, Wq, v);
  attn_kernel <<<512, 1024, 0, stream>>>(x, pe, v, g, out);
}